// Round 5
// baseline (35088.403 us; speedup 1.0000x reference)
//
#include <hip/hip_runtime.h>
#include <math.h>
#include <stdint.h>
#include <limits.h>

#define VSZ 50257
#define VP  50304           // padded vocab stride (786*64)
#define ESZ 256
#define HSZ 1024
#define BSZ 64
#define TSZ 80
#define GC  4096            // 4*H gate columns
#define NFCB 786            // ceil(VSZ/64) merge/top5 col-blocks
#define NCAND (NFCB*5)      // 3930 candidates per batch row
#define NSLOT 26            // lstm part slots: A 0..17, B 18..25 (fc partials alias this)

typedef unsigned int u32;

// ---------------- Threefry-2x32 (JAX exact) ----------------
__device__ __forceinline__ void tf2x32(u32 k0, u32 k1, u32& x0, u32& x1) {
  u32 ks2 = k0 ^ k1 ^ 0x1BD11BDAu;
  x0 += k0; x1 += k1;
#define RND(r) { x0 += x1; x1 = (x1 << r) | (x1 >> (32 - r)); x1 ^= x0; }
  RND(13) RND(15) RND(26) RND(6)
  x0 += k1; x1 += ks2 + 1u;
  RND(17) RND(29) RND(16) RND(24)
  x0 += ks2; x1 += k0 + 2u;
  RND(13) RND(15) RND(26) RND(6)
  x0 += k0; x1 += k1 + 3u;
  RND(17) RND(29) RND(16) RND(24)
  x0 += k1; x1 += ks2 + 4u;
  RND(13) RND(15) RND(26) RND(6)
  x0 += ks2; x1 += k0 + 5u;
#undef RND
}

__device__ __forceinline__ double dsig(double x) { return 0.5 + 0.5 * tanh(0.5 * x); }

// sorted-desc top5 insert; ties -> lower index first (matches lax.top_k)
__device__ __forceinline__ void ins5(double v, int i, double* tv, int* ti) {
  bool beat4 = (v > tv[4]) || (v == tv[4] && i < ti[4]);
  if (!beat4) return;
  tv[4] = v; ti[4] = i;
#pragma unroll
  for (int p = 4; p > 0; --p) {
    bool sw = (tv[p] > tv[p-1]) || (tv[p] == tv[p-1] && ti[p] < ti[p-1]);
    double a0 = sw ? tv[p] : tv[p-1]; double a1 = sw ? tv[p-1] : tv[p];
    tv[p-1] = a0; tv[p] = a1;
    int b0 = sw ? ti[p] : ti[p-1]; int b1 = sw ? ti[p-1] : ti[p];
    ti[p-1] = b0; ti[p] = b1;
  }
}

// -------- fused RNG: gumbel[t][m] for t<80, m<320 --------
__global__ __launch_bounds__(256) void k_rng(double* __restrict__ gum) {
  int idx = blockIdx.x * 256 + threadIdx.x;
  if (idx >= TSZ * 320) return;
  int t = idx / 320, m = idx % 320;
  u32 a0 = 0u, a1 = (u32)t;
  tf2x32(0u, 42u, a0, a1);
  u32 x0 = 0u, x1 = (u32)m;
  tf2x32(a0, a1, x0, x1);
  u32 bits = x0 ^ x1;
  const float TINY = 1.17549435082228750797e-38f;  // 2^-126
  float f = __uint_as_float((bits >> 9) | 0x3f800000u) - 1.0f;
  float u = f + TINY;
  u = fmaxf(TINY, u);
  gum[idx] = -log(-log((double)u));
}

// -------- time encode stage 1 --------
__global__ __launch_bounds__(256) void k_time1(const float* __restrict__ hours, const float* __restrict__ w1,
                                               const float* __restrict__ bb1, double* __restrict__ tp1T) {
  int idx = blockIdx.x * 256 + threadIdx.x;  // 64*1024
  int b = idx & 63, hcol = idx >> 6;
  const float TPO = (float)(2.0 * 3.14159265358979323846 / 24.0);
  float af = hours[b] * TPO;
  double a = (double)af;
  double sv = sin(a), cv = cos(a);
  double vv = tanh(sv * (double)w1[hcol] + cv * (double)w1[HSZ + hcol] + (double)bb1[hcol]);
  tp1T[(size_t)hcol * 64 + b] = vv;
}

// -------- simple split-K gemm (prologue-only, runs once) --------
__global__ __launch_bounds__(256) void k_gemm_simple(const double* __restrict__ XTa, const float* __restrict__ Wa,
                                                     int Ka, int Sa, double* __restrict__ part) {
  int j = blockIdx.x * 256 + threadIdx.x;
  if (j >= GC) return;
  int s = blockIdx.y;
  int kc = Ka / Sa, k0 = s * kc;
  double acc[BSZ];
#pragma unroll
  for (int b = 0; b < BSZ; ++b) acc[b] = 0.0;
  const float* wp = Wa + (size_t)k0 * GC + j;
  const double* xp = XTa + (size_t)k0 * 64;
  for (int k = 0; k < kc; ++k) {
    double wv = (double)wp[0]; wp += GC;
#pragma unroll
    for (int b = 0; b < BSZ; ++b) acc[b] = fma(wv, xp[b], acc[b]);
    xp += 64;
  }
  double* o = part + ((size_t)s * 64) * GC + j;
#pragma unroll
  for (int b = 0; b < BSZ; ++b) o[(size_t)b * GC] = acc[b];
}

// -------- time encode stage 2 reduce --------
__global__ __launch_bounds__(256) void k_t2r(const double* __restrict__ part, const float* __restrict__ b2,
                                             double* __restrict__ h0T, double* __restrict__ c0,
                                             double* __restrict__ h1T, double* __restrict__ c1) {
  int b = blockIdx.y;
  int j = blockIdx.x * 256 + threadIdx.x;
  double acc = (double)b2[j];
  for (int s = 0; s < 8; ++s) acc += part[((size_t)s * 64 + b) * GC + j];
  int l = j >> 11, half = (j >> 10) & 1, hcol = j & 1023;
  if (half == 0) (l ? h1T : h0T)[(size_t)hcol * 64 + b] = acc;
  else           (l ? c1 : c0)[(size_t)b * HSZ + hcol] = acc;
}

// -------- LSTM gemm: C=4 cols x B=4 batches per thread, 16-lane col groups --------
// grid (64, S). slice s: s<s1 -> (x0,W0,k0=s*128); s<s2 -> (x1,W1,(s-s1)*128); else (x2,W2,(s-s2)*128)
__global__ __launch_bounds__(256, 4) void k_lstm(const double* __restrict__ x0, const float* __restrict__ W0,
                                                 const double* __restrict__ x1, const float* __restrict__ W1,
                                                 const double* __restrict__ x2, const float* __restrict__ W2,
                                                 int s1, int s2, double* __restrict__ part) {
  __shared__ double xs[64 * 64];   // 32KB x-chunk
  int tid = threadIdx.x;
  int vg = tid & 15, bg = tid >> 4;           // 16 col-lanes, 16 batch groups x 4 b
  int colbase = blockIdx.x * 64;
  int s = blockIdx.y;
  const double* XT; const float* W; int k0;
  if (s < s1)      { XT = x0; W = W0; k0 = s * 128; }
  else if (s < s2) { XT = x1; W = W1; k0 = (s - s1) * 128; }
  else             { XT = x2; W = W2; k0 = (s - s2) * 128; }
  double acc[4][4];
#pragma unroll
  for (int i = 0; i < 4; ++i)
#pragma unroll
    for (int j = 0; j < 4; ++j) acc[i][j] = 0.0;
  float wb[4][4];

#define LFMA(U, KIDX)                                                                  \
  {                                                                                    \
    const double2* xp = (const double2*)xs + ((KIDX) << 5) + (bg << 1);                \
    double2 xa = xp[0], xb = xp[1];                                                    \
    double w0 = (double)wb[U][0], w1 = (double)wb[U][1];                               \
    double w2 = (double)wb[U][2], w3 = (double)wb[U][3];                               \
    acc[0][0] = fma(w0, xa.x, acc[0][0]); acc[0][1] = fma(w0, xa.y, acc[0][1]);        \
    acc[0][2] = fma(w0, xb.x, acc[0][2]); acc[0][3] = fma(w0, xb.y, acc[0][3]);        \
    acc[1][0] = fma(w1, xa.x, acc[1][0]); acc[1][1] = fma(w1, xa.y, acc[1][1]);        \
    acc[1][2] = fma(w1, xb.x, acc[1][2]); acc[1][3] = fma(w1, xb.y, acc[1][3]);        \
    acc[2][0] = fma(w2, xa.x, acc[2][0]); acc[2][1] = fma(w2, xa.y, acc[2][1]);        \
    acc[2][2] = fma(w2, xb.x, acc[2][2]); acc[2][3] = fma(w2, xb.y, acc[2][3]);        \
    acc[3][0] = fma(w3, xa.x, acc[3][0]); acc[3][1] = fma(w3, xa.y, acc[3][1]);        \
    acc[3][2] = fma(w3, xb.x, acc[3][2]); acc[3][3] = fma(w3, xb.y, acc[3][3]);        \
  }

  for (int ch = 0; ch < 2; ++ch) {
    const float* wr = W + (size_t)(k0 + ch * 64) * GC + colbase + vg;
    // preload rows 0..3 (in flight across barrier + staging)
#pragma unroll
    for (int u = 0; u < 4; ++u) {
      wb[u][0] = wr[0]; wb[u][1] = wr[16]; wb[u][2] = wr[32]; wb[u][3] = wr[48];
      wr += GC;
    }
    __syncthreads();
    const double2* src = (const double2*)(XT + (size_t)(k0 + ch * 64) * 64);
    double2* dst = (double2*)xs;
    for (int i = tid; i < 2048; i += 256) dst[i] = src[i];
    __syncthreads();
    for (int kk = 0; kk < 60; kk += 4) {
#pragma unroll
      for (int u = 0; u < 4; ++u) {
        float n0 = wr[0], n1 = wr[16], n2 = wr[32], n3 = wr[48]; wr += GC;
        LFMA(u, kk + u)
        wb[u][0] = n0; wb[u][1] = n1; wb[u][2] = n2; wb[u][3] = n3;
      }
    }
#pragma unroll
    for (int u = 0; u < 4; ++u) { LFMA(u, 60 + u) }
  }
#undef LFMA
#pragma unroll
  for (int i = 0; i < 4; ++i)
#pragma unroll
    for (int j = 0; j < 4; ++j) {
      int b = bg * 4 + j;
      part[((size_t)s * 64 + b) * GC + colbase + vg + 16 * i] = acc[i][j];
    }
}

// -------- LSTM cell: sum partial slots [sBeg, sBeg+S) + bias; gates i,f,g,o --------
__global__ __launch_bounds__(256) void k_cell(const double* __restrict__ part, int sBeg, int S,
                                              const float* __restrict__ bias,
                                              double* __restrict__ c, double* __restrict__ hT) {
  int b = blockIdx.y;
  int hcol = blockIdx.x * 256 + threadIdx.x;
  double gi = (double)bias[hcol];
  double gf = (double)bias[1024 + hcol];
  double gg = (double)bias[2048 + hcol];
  double go = (double)bias[3072 + hcol];
#pragma unroll 4
  for (int s = sBeg; s < sBeg + S; ++s) {
    const double* p = part + ((size_t)s * 64 + b) * GC;
    gi += p[hcol]; gf += p[1024 + hcol]; gg += p[2048 + hcol]; go += p[3072 + hcol];
  }
  size_t ci = (size_t)b * HSZ + hcol;
  double cn = dsig(gf) * c[ci] + dsig(gi) * tanh(gg);
  double hn = dsig(go) * tanh(cn);
  c[ci] = cn;
  hT[(size_t)hcol * 64 + b] = hn;
}

// -------- FC partials: C=4 cols x B=8 batches, K-split=2, grid (393, 2) --------
// writes partfc[y][b][v] (stride VP), v-pad region holds garbage (masked at merge)
__global__ __launch_bounds__(256, 4) void k_fcpart(const double* __restrict__ h1T, const float* __restrict__ W,
                                                   double* __restrict__ partfc) {
  __shared__ double xs[64 * 64];   // 32KB x-chunk
  int tid = threadIdx.x;
  int vg = tid & 31, bg = tid >> 5;          // 32 col-lanes, 8 batch groups x 8 b
  int vbase = blockIdx.x * 128;
  int y = blockIdx.y;
  int kbase = y * 512;
  int c0 = min(vbase + vg,      VSZ - 1);
  int c1 = min(vbase + vg + 32, VSZ - 1);
  int c2 = min(vbase + vg + 64, VSZ - 1);
  int c3 = min(vbase + vg + 96, VSZ - 1);
  double acc[4][8];
#pragma unroll
  for (int i = 0; i < 4; ++i)
#pragma unroll
    for (int j = 0; j < 8; ++j) acc[i][j] = 0.0;
  float wb[4][4];

#define FFMA(U, KIDX)                                                                  \
  {                                                                                    \
    const double2* xp = (const double2*)xs + ((KIDX) << 5) + (bg << 2);                \
    double2 xa = xp[0], xb = xp[1], xc = xp[2], xd = xp[3];                            \
    double w0 = (double)wb[U][0], w1 = (double)wb[U][1];                               \
    double w2 = (double)wb[U][2], w3 = (double)wb[U][3];                               \
    acc[0][0] = fma(w0, xa.x, acc[0][0]); acc[0][1] = fma(w0, xa.y, acc[0][1]);        \
    acc[0][2] = fma(w0, xb.x, acc[0][2]); acc[0][3] = fma(w0, xb.y, acc[0][3]);        \
    acc[0][4] = fma(w0, xc.x, acc[0][4]); acc[0][5] = fma(w0, xc.y, acc[0][5]);        \
    acc[0][6] = fma(w0, xd.x, acc[0][6]); acc[0][7] = fma(w0, xd.y, acc[0][7]);        \
    acc[1][0] = fma(w1, xa.x, acc[1][0]); acc[1][1] = fma(w1, xa.y, acc[1][1]);        \
    acc[1][2] = fma(w1, xb.x, acc[1][2]); acc[1][3] = fma(w1, xb.y, acc[1][3]);        \
    acc[1][4] = fma(w1, xc.x, acc[1][4]); acc[1][5] = fma(w1, xc.y, acc[1][5]);        \
    acc[1][6] = fma(w1, xd.x, acc[1][6]); acc[1][7] = fma(w1, xd.y, acc[1][7]);        \
    acc[2][0] = fma(w2, xa.x, acc[2][0]); acc[2][1] = fma(w2, xa.y, acc[2][1]);        \
    acc[2][2] = fma(w2, xb.x, acc[2][2]); acc[2][3] = fma(w2, xb.y, acc[2][3]);        \
    acc[2][4] = fma(w2, xc.x, acc[2][4]); acc[2][5] = fma(w2, xc.y, acc[2][5]);        \
    acc[2][6] = fma(w2, xd.x, acc[2][6]); acc[2][7] = fma(w2, xd.y, acc[2][7]);        \
    acc[3][0] = fma(w3, xa.x, acc[3][0]); acc[3][1] = fma(w3, xa.y, acc[3][1]);        \
    acc[3][2] = fma(w3, xb.x, acc[3][2]); acc[3][3] = fma(w3, xb.y, acc[3][3]);        \
    acc[3][4] = fma(w3, xc.x, acc[3][4]); acc[3][5] = fma(w3, xc.y, acc[3][5]);        \
    acc[3][6] = fma(w3, xd.x, acc[3][6]); acc[3][7] = fma(w3, xd.y, acc[3][7]);        \
  }

  for (int ch = 0; ch < 8; ++ch) {
    const float* wr = W + (size_t)(kbase + ch * 64) * VSZ;
#pragma unroll
    for (int u = 0; u < 4; ++u) {
      wb[u][0] = wr[c0]; wb[u][1] = wr[c1]; wb[u][2] = wr[c2]; wb[u][3] = wr[c3];
      wr += VSZ;
    }
    __syncthreads();
    const double2* src = (const double2*)(h1T + (size_t)(kbase + ch * 64) * 64);
    double2* dst = (double2*)xs;
    for (int i = tid; i < 2048; i += 256) dst[i] = src[i];
    __syncthreads();
    for (int kk = 0; kk < 60; kk += 4) {
#pragma unroll
      for (int u = 0; u < 4; ++u) {
        float n0 = wr[c0], n1 = wr[c1], n2 = wr[c2], n3 = wr[c3]; wr += VSZ;
        FFMA(u, kk + u)
        wb[u][0] = n0; wb[u][1] = n1; wb[u][2] = n2; wb[u][3] = n3;
      }
    }
#pragma unroll
    for (int u = 0; u < 4; ++u) { FFMA(u, 60 + u) }
  }
#undef FFMA
#pragma unroll
  for (int i = 0; i < 4; ++i)
#pragma unroll
    for (int j = 0; j < 8; ++j) {
      int b = bg * 8 + j;
      partfc[((size_t)y * 64 + b) * VP + vbase + vg + 32 * i] = acc[i][j];
    }
}

// -------- merge K-halves + bias + /TEMP + per-64col top5 --------
__global__ __launch_bounds__(256) void k_fctop5(const double* __restrict__ partfc, const float* __restrict__ fcb,
                                                double* __restrict__ candV, int* __restrict__ candI) {
  __shared__ double xs[64 * 64];   // 32KB transpose buffer
  int tid = threadIdx.x;
  int vbase = blockIdx.x * 64;
  int vl = tid & 63, br = tid >> 6;            // 64 v-lanes, 4 b-rows
  int v = vbase + vl;
  bool ok = (v < VSZ);
  double bi = ok ? (double)fcb[min(v, VSZ - 1)] : 0.0;
#pragma unroll
  for (int j = 0; j < 16; ++j) {
    int b = br * 16 + j;
    double val = ok ? (partfc[(size_t)b * VP + v] + partfc[((size_t)64 + b) * VP + v] + bi) / 0.75
                    : -INFINITY;
    xs[b * 64 + ((vl + b) & 63)] = val;        // swizzled (conflict-free)
  }
  __syncthreads();
  if (tid < 64) {
    int b = tid;
    double tv[5]; int ti[5];
#pragma unroll
    for (int p = 0; p < 5; ++p) { tv[p] = -INFINITY; ti[p] = INT_MAX; }
    for (int vl2 = 0; vl2 < 64; ++vl2)
      ins5(xs[b * 64 + ((vl2 + b) & 63)], vbase + vl2, tv, ti);
#pragma unroll
    for (int r = 0; r < 5; ++r) {
      candV[(size_t)b * NCAND + blockIdx.x * 5 + r] = tv[r];
      candI[(size_t)b * NCAND + blockIdx.x * 5 + r] = ti[r];
    }
  }
}

// -------- final merge (3930 cands, b-major/coalesced) + gumbel sample + outputs --------
__global__ __launch_bounds__(64) void k_fin(const double* __restrict__ candV, const int* __restrict__ candI,
                                            const double* __restrict__ gum, int t,
                                            const float* __restrict__ embed,
                                            float* __restrict__ out, double* __restrict__ xt0) {
  int b = blockIdx.x, lane = threadIdx.x;
  double tv[5]; int ti[5];
#pragma unroll
  for (int p = 0; p < 5; ++p) { tv[p] = -INFINITY; ti[p] = INT_MAX; }
  const double* cv = candV + (size_t)b * NCAND;
  const int*    ci = candI + (size_t)b * NCAND;
  for (int e = lane; e < NCAND; e += 64)
    ins5(cv[e], ci[e], tv, ti);
  double mv[5]; int mi[5];
#pragma unroll
  for (int r = 0; r < 5; ++r) {
    double bv = tv[0]; int bi = ti[0];
    for (int off = 1; off < 64; off <<= 1) {
      double ov = __shfl_xor(bv, off, 64);
      int oi = __shfl_xor(bi, off, 64);
      if (ov > bv || (ov == bv && oi < bi)) { bv = ov; bi = oi; }
    }
    mv[r] = bv; mi[r] = bi;
    if (tv[0] == bv && ti[0] == bi) {
#pragma unroll
      for (int p = 0; p < 4; ++p) { tv[p] = tv[p+1]; ti[p] = ti[p+1]; }
      tv[4] = -INFINITY; ti[4] = INT_MAX;
    }
  }
  const double* g = gum + (size_t)t * 320 + b * 5;
  double bestv = mv[0] + g[0]; int best = 0;
#pragma unroll
  for (int k2 = 1; k2 < 5; ++k2) { double vv = mv[k2] + g[k2]; if (vv > bestv) { bestv = vv; best = k2; } }
  int nxt = mi[best];
  if (lane == 0) {
    out[b * TSZ + t] = (float)nxt;
    double m = mv[0];
    double ex[5]; double s = 0.0;
#pragma unroll
    for (int k2 = 0; k2 < 5; ++k2) { ex[k2] = exp(mv[k2] - m); s += ex[k2]; }
    float* po = out + BSZ * TSZ + ((size_t)b * TSZ + t) * 5;
#pragma unroll
    for (int k2 = 0; k2 < 5; ++k2) po[k2] = (float)(ex[k2] / s);
  }
  for (int k = lane; k < ESZ; k += 64)
    xt0[(size_t)k * 64 + b] = (double)embed[(size_t)nxt * ESZ + k];
}

// -------- initial embedding of SOS --------
__global__ __launch_bounds__(256) void k_emb0(const float* __restrict__ embed, const int* __restrict__ sos,
                                              double* __restrict__ xt0) {
  int idx = blockIdx.x * 256 + threadIdx.x;
  int b = idx & 63, k = idx >> 6;
  xt0[(size_t)k * 64 + b] = (double)embed[(size_t)sos[0] * ESZ + k];
}

extern "C" void kernel_launch(void* const* d_in, const int* in_sizes, int n_in,
                              void* d_out, int out_size, void* d_ws, size_t ws_size,
                              hipStream_t stream) {
  const float* hours = (const float*)d_in[0];
  const float* tp_w1 = (const float*)d_in[1];
  const float* tp_b1 = (const float*)d_in[2];
  const float* tp_w2 = (const float*)d_in[3];
  const float* tp_b2 = (const float*)d_in[4];
  const float* embed = (const float*)d_in[5];
  const float* w_ih0 = (const float*)d_in[6];
  const float* w_hh0 = (const float*)d_in[7];
  const float* b0    = (const float*)d_in[8];
  const float* w_ih1 = (const float*)d_in[9];
  const float* w_hh1 = (const float*)d_in[10];
  const float* b1    = (const float*)d_in[11];
  const float* fc_w  = (const float*)d_in[12];
  const float* fc_b  = (const float*)d_in[13];
  const int*   sos   = (const int*)d_in[14];
  float* out = (float*)d_out;

  char* w = (char*)d_ws;
  double* part = (double*)w;  w += (size_t)NSLOT * 64 * GC * 8;   // 54.5 MB lstm partials
  double* partfc = part;      // fc partials alias (2*64*VP*8 = 51.5 MB <= 54.5, stream-ordered safe)
  double* xt0  = (double*)w;  w += (size_t)ESZ * 64 * 8;
  double* h0T  = (double*)w;  w += (size_t)HSZ * 64 * 8;
  double* h1T  = (double*)w;  w += (size_t)HSZ * 64 * 8;
  double* c0   = (double*)w;  w += (size_t)BSZ * HSZ * 8;
  double* c1   = (double*)w;  w += (size_t)BSZ * HSZ * 8;
  double* tp1T = (double*)w;  w += (size_t)HSZ * 64 * 8;
  double* gum  = (double*)w;  w += (size_t)TSZ * 320 * 8;
  double* candV = (double*)w; w += (size_t)BSZ * NCAND * 8;       // 2.01 MB, b-major
  int*    candI = (int*)w;    w += (size_t)BSZ * NCAND * 4;       // 1.01 MB

  k_rng<<<dim3(100), dim3(256), 0, stream>>>(gum);
  k_time1<<<dim3(256), dim3(256), 0, stream>>>(hours, tp_w1, tp_b1, tp1T);
  k_gemm_simple<<<dim3(16, 8), dim3(256), 0, stream>>>(tp1T, tp_w2, 1024, 8, part);
  k_t2r<<<dim3(16, 64), dim3(256), 0, stream>>>(part, tp_b2, h0T, c0, h1T, c1);
  k_emb0<<<dim3(64), dim3(256), 0, stream>>>(embed, sos, xt0);

  double* part18 = part + (size_t)18 * 64 * GC;
  for (int t = 0; t < TSZ; ++t) {
    // A: slices 0-1 = xt0*w_ih0, 2-9 = h0*w_hh0, 10-17 = h1*w_hh1
    k_lstm<<<dim3(64, 18), dim3(256), 0, stream>>>(xt0, w_ih0, h0T, w_hh0, h1T, w_hh1, 2, 10, part);
    k_cell<<<dim3(4, 64), dim3(256), 0, stream>>>(part, 0, 10, b0, c0, h0T);
    // B: slices 0-7 = h0n*w_ih1 -> slots 18-25
    k_lstm<<<dim3(64, 8), dim3(256), 0, stream>>>(h0T, w_ih1, h0T, w_ih1, h0T, w_ih1, 8, 8, part18);
    k_cell<<<dim3(4, 64), dim3(256), 0, stream>>>(part, 10, 16, b1, c1, h1T);
    // FC partials overwrite part (dead until next lstmA) then merge+top5
    k_fcpart<<<dim3(393, 2), dim3(256), 0, stream>>>(h1T, fc_w, partfc);
    k_fctop5<<<dim3(NFCB), dim3(256), 0, stream>>>(partfc, fc_b, candV, candI);
    k_fin<<<dim3(64), dim3(64), 0, stream>>>(candV, candI, gum, t, embed, out, xt0);
  }
}

// Round 8
// 26086.066 us; speedup vs baseline: 1.3451x; 1.3451x over previous
//
#include <hip/hip_runtime.h>
#include <math.h>
#include <stdint.h>
#include <limits.h>

#define VSZ 50257
#define ESZ 256
#define HSZ 1024
#define BSZ 64
#define TSZ 80
#define GC  4096            // 4*H gate columns
#define NFCB 786            // ceil(VSZ/64) FC col-blocks
#define NCAND (NFCB*5)      // 3930 candidates per batch row
#define NSLOT 26            // lstm part slots: A 0..17, B 18..25

typedef unsigned int u32;
typedef double f64x4 __attribute__((ext_vector_type(4)));

// ---------------- Threefry-2x32 (JAX exact) ----------------
__device__ __forceinline__ void tf2x32(u32 k0, u32 k1, u32& x0, u32& x1) {
  u32 ks2 = k0 ^ k1 ^ 0x1BD11BDAu;
  x0 += k0; x1 += k1;
#define RND(r) { x0 += x1; x1 = (x1 << r) | (x1 >> (32 - r)); x1 ^= x0; }
  RND(13) RND(15) RND(26) RND(6)
  x0 += k1; x1 += ks2 + 1u;
  RND(17) RND(29) RND(16) RND(24)
  x0 += ks2; x1 += k0 + 2u;
  RND(13) RND(15) RND(26) RND(6)
  x0 += k0; x1 += k1 + 3u;
  RND(17) RND(29) RND(16) RND(24)
  x0 += k1; x1 += ks2 + 4u;
  RND(13) RND(15) RND(26) RND(6)
  x0 += ks2; x1 += k0 + 5u;
#undef RND
}

__device__ __forceinline__ double dsig(double x) { return 0.5 + 0.5 * tanh(0.5 * x); }

// sorted-desc top5 insert; ties -> lower index first (matches lax.top_k)
__device__ __forceinline__ void ins5(double v, int i, double* tv, int* ti) {
  bool beat4 = (v > tv[4]) || (v == tv[4] && i < ti[4]);
  if (!beat4) return;
  tv[4] = v; ti[4] = i;
#pragma unroll
  for (int p = 4; p > 0; --p) {
    bool sw = (tv[p] > tv[p-1]) || (tv[p] == tv[p-1] && ti[p] < ti[p-1]);
    double a0 = sw ? tv[p] : tv[p-1]; double a1 = sw ? tv[p-1] : tv[p];
    tv[p-1] = a0; tv[p] = a1;
    int b0 = sw ? ti[p] : ti[p-1]; int b1 = sw ? ti[p-1] : ti[p];
    ti[p-1] = b0; ti[p] = b1;
  }
}

// exact integer reference D[m][n] for the probe: sum_k (4m+k+1)*(16k+n+1)
__device__ __forceinline__ double dref(int m, int n) {
  int s = 0;
#pragma unroll
  for (int k = 0; k < 4; ++k) s += (4*m + k + 1) * (16*k + n + 1);
  return (double)s;
}

// -------- MFMA layout probe: fb[0] = conv index (0..3) or 255; fb[1] = bad flag (reset 0) --------
// conv0: D[4*sub+j][lane16]  conv1: D[lane16][4*sub+j]
// conv2: D[sub+4*j][lane16]  conv3: D[lane16][sub+4*j]
__global__ __launch_bounds__(64) void k_probe(int* __restrict__ fb) {
  int l = threadIdx.x;
  int lane16 = l & 15, sub = l >> 4;
  double av = (double)(4 * lane16 + sub + 1);     // A[m=lane16][k=sub]
  double bv = (double)(16 * sub + lane16 + 1);    // B[k=sub][n=lane16]
  f64x4 acc = {0., 0., 0., 0.};
  acc = __builtin_amdgcn_mfma_f64_16x16x4f64(av, bv, acc, 0, 0, 0);
  bool o0 = true, o1 = true, o2 = true, o3 = true;
#pragma unroll
  for (int j = 0; j < 4; ++j) {
    double d = acc[j];
    o0 = o0 && (d == dref(4 * sub + j, lane16));
    o1 = o1 && (d == dref(lane16, 4 * sub + j));
    o2 = o2 && (d == dref(sub + 4 * j, lane16));
    o3 = o3 && (d == dref(lane16, sub + 4 * j));
  }
  int a0 = __all(o0), a1 = __all(o1), a2 = __all(o2), a3 = __all(o3);
  if (l == 0) {
    fb[0] = a0 ? 0 : a1 ? 1 : a2 ? 2 : a3 ? 3 : 255;
    fb[1] = 0;
  }
}

// -------- fused RNG: gumbel[t][m] for t<80, m<320 --------
__global__ __launch_bounds__(256) void k_rng(double* __restrict__ gum) {
  int idx = blockIdx.x * 256 + threadIdx.x;
  if (idx >= TSZ * 320) return;
  int t = idx / 320, m = idx % 320;
  u32 a0 = 0u, a1 = (u32)t;
  tf2x32(0u, 42u, a0, a1);
  u32 x0 = 0u, x1 = (u32)m;
  tf2x32(a0, a1, x0, x1);
  u32 bits = x0 ^ x1;
  const float TINY = 1.17549435082228750797e-38f;  // 2^-126
  float f = __uint_as_float((bits >> 9) | 0x3f800000u) - 1.0f;
  float u = f + TINY;
  u = fmaxf(TINY, u);
  gum[idx] = -log(-log((double)u));
}

// -------- time encode stage 1 --------
__global__ __launch_bounds__(256) void k_time1(const float* __restrict__ hours, const float* __restrict__ w1,
                                               const float* __restrict__ bb1, double* __restrict__ tp1T) {
  int idx = blockIdx.x * 256 + threadIdx.x;  // 64*1024
  int b = idx & 63, hcol = idx >> 6;
  const float TPO = (float)(2.0 * 3.14159265358979323846 / 24.0);
  float af = hours[b] * TPO;
  double a = (double)af;
  double sv = sin(a), cv = cos(a);
  double vv = tanh(sv * (double)w1[hcol] + cv * (double)w1[HSZ + hcol] + (double)bb1[hcol]);
  tp1T[(size_t)hcol * 64 + b] = vv;
}

// -------- simple split-K gemm (prologue-only, runs once) --------
__global__ __launch_bounds__(256) void k_gemm_simple(const double* __restrict__ XTa, const float* __restrict__ Wa,
                                                     int Ka, int Sa, double* __restrict__ part) {
  int j = blockIdx.x * 256 + threadIdx.x;
  if (j >= GC) return;
  int s = blockIdx.y;
  int kc = Ka / Sa, k0 = s * kc;
  double acc[BSZ];
#pragma unroll
  for (int b = 0; b < BSZ; ++b) acc[b] = 0.0;
  const float* wp = Wa + (size_t)k0 * GC + j;
  const double* xp = XTa + (size_t)k0 * 64;
  for (int k = 0; k < kc; ++k) {
    double wv = (double)wp[0]; wp += GC;
#pragma unroll
    for (int b = 0; b < BSZ; ++b) acc[b] = fma(wv, xp[b], acc[b]);
    xp += 64;
  }
  double* o = part + ((size_t)s * 64) * GC + j;
#pragma unroll
  for (int b = 0; b < BSZ; ++b) o[(size_t)b * GC] = acc[b];
}

// -------- time encode stage 2 reduce --------
__global__ __launch_bounds__(256) void k_t2r(const double* __restrict__ part, const float* __restrict__ b2,
                                             double* __restrict__ h0T, double* __restrict__ c0,
                                             double* __restrict__ h1T, double* __restrict__ c1) {
  int b = blockIdx.y;
  int j = blockIdx.x * 256 + threadIdx.x;
  double acc = (double)b2[j];
  for (int s = 0; s < 8; ++s) acc += part[((size_t)s * 64 + b) * GC + j];
  int l = j >> 11, half = (j >> 10) & 1, hcol = j & 1023;
  if (half == 0) (l ? h1T : h0T)[(size_t)hcol * 64 + b] = acc;
  else           (l ? c1 : c0)[(size_t)b * HSZ + hcol] = acc;
}

// ================= MFMA path (guarded by probe + per-block end-to-end verify) =================

// -------- LSTM gemm via f64 MFMA; conv-parameterized D write; part[s][b][col] --------
__global__ __launch_bounds__(256, 4) void k_lstm_mfma(const double* __restrict__ x0, const float* __restrict__ W0,
                                                      const double* __restrict__ x1, const float* __restrict__ W1,
                                                      const double* __restrict__ x2, const float* __restrict__ W2,
                                                      int s1, int s2, double* __restrict__ part,
                                                      const int* __restrict__ fb, int* __restrict__ fbw) {
  int conv = fb[0];
  if (conv >= 4 || fb[1] != 0) return;
  __shared__ double xs[64 * 64];   // 32KB x-chunk [k][b]
  __shared__ int okS;
  int tid = threadIdx.x;
  int l = tid & 63, wv = tid >> 6;
  int sub = l >> 4, lane16 = l & 15;
  int colbase = blockIdx.x * 64;
  int s = blockIdx.y;
  const double* XT; const float* W; int k0;
  if (s < s1)      { XT = x0; W = W0; k0 = s * 128; }
  else if (s < s2) { XT = x1; W = W1; k0 = (s - s1) * 128; }
  else             { XT = x2; W = W2; k0 = (s - s2) * 128; }
  int colA = colbase + wv * 16 + lane16;
  f64x4 a0 = {0.,0.,0.,0.}, a1 = {0.,0.,0.,0.}, a2 = {0.,0.,0.,0.}, a3 = {0.,0.,0.,0.};
  const float* wp = W + (size_t)(k0 + sub) * GC + colA;
  float aC = wp[0]; wp += (size_t)4 * GC;
  float aN = wp[0]; wp += (size_t)4 * GC;
  for (int ch = 0; ch < 2; ++ch) {
    __syncthreads();
    const double2* src = (const double2*)(XT + (size_t)(k0 + ch * 64) * 64);
    double2* dst = (double2*)xs;
    for (int i = tid; i < 2048; i += 256) dst[i] = src[i];
    __syncthreads();
    for (int ks = 0; ks < 16; ++ks) {
      int gks = ch * 16 + ks;
      float aP = 0.f;
      if (gks + 2 < 32) aP = wp[0];
      wp += (size_t)4 * GC;
      double av = (double)aC;
      const double* bp = xs + (ks * 4 + sub) * 64 + lane16;
      double b0 = bp[0], b1 = bp[16], b2 = bp[32], b3 = bp[48];
      a0 = __builtin_amdgcn_mfma_f64_16x16x4f64(av, b0, a0, 0, 0, 0);
      a1 = __builtin_amdgcn_mfma_f64_16x16x4f64(av, b1, a1, 0, 0, 0);
      a2 = __builtin_amdgcn_mfma_f64_16x16x4f64(av, b2, a2, 0, 0, 0);
      a3 = __builtin_amdgcn_mfma_f64_16x16x4f64(av, b3, a3, 0, 0, 0);
      aC = aN; aN = aP;
    }
  }
  // end-to-end verify: D(m=1,n=0) and D(m=1,n=48) vs serial f64 refs
  if (wv == 0) {
    double r0 = 0.0, r48 = 0.0;
#pragma unroll
    for (int q = 0; q < 2; ++q) {
      int k = k0 + q * 64 + l;
      double wvv = (double)W[(size_t)k * GC + colbase + 1];
      r0  += wvv * XT[(size_t)k * 64];
      r48 += wvv * XT[(size_t)k * 64 + 48];
    }
#pragma unroll
    for (int off = 1; off < 64; off <<= 1) {
      r0  += __shfl_xor(r0, off, 64);
      r48 += __shfl_xor(r48, off, 64);
    }
    int lsel = (conv == 0) ? 0 : (conv == 2) ? 16 : 1;
    int rsel = (conv == 0) ? 1 : 0;
    double g0a = __shfl(a0[0], lsel, 64), g0b = __shfl(a0[1], lsel, 64);
    double g3a = __shfl(a3[0], lsel, 64), g3b = __shfl(a3[1], lsel, 64);
    double got0  = rsel ? g0b : g0a;
    double got48 = rsel ? g3b : g3a;
    bool ok = (fabs(got0 - r0)   <= 1e-9 * (1.0 + fabs(r0))) &&
              (fabs(got48 - r48) <= 1e-9 * (1.0 + fabs(r48)));
    if (l == 0) { okS = ok ? 1 : 0; if (!ok) atomicOr(fbw, 1); }
  }
  __syncthreads();
  if (!okS) return;   // uniform; fallback kernel will redo everything
#pragma unroll
  for (int j = 0; j < 4; ++j) {
    int m = (conv == 0) ? sub * 4 + j : (conv == 2) ? sub + 4 * j : lane16;
    int n = (conv == 0) ? lane16 : (conv == 2) ? lane16 : ((conv == 1) ? sub * 4 + j : sub + 4 * j);
    size_t base = ((size_t)s * 64 + n) * GC + colbase + wv * 16 + m;
    part[base]                   = a0[j];
    part[base + (size_t)16 * GC] = a1[j];
    part[base + (size_t)32 * GC] = a2[j];
    part[base + (size_t)48 * GC] = a3[j];
  }
}

// -------- FC via f64 MFMA + fused top5; conv-parameterized; per-block verify --------
__global__ __launch_bounds__(256, 4) void k_fcmfma(const double* __restrict__ h1T, const float* __restrict__ W,
                                                   const float* __restrict__ fcb,
                                                   double* __restrict__ candV, int* __restrict__ candI,
                                                   const int* __restrict__ fb, int* __restrict__ fbw) {
  int conv = fb[0];
  if (conv >= 4 || fb[1] != 0) return;
  __shared__ double xs[64 * 64];   // x-chunk staging, then transpose buffer
  __shared__ int okS;
  int tid = threadIdx.x;
  int l = tid & 63, wv = tid >> 6;
  int sub = l >> 4, lane16 = l & 15;
  int vbase = blockIdx.x * 64;
  int colA = min(vbase + wv * 16 + lane16, VSZ - 1);
  f64x4 a0 = {0.,0.,0.,0.}, a1 = {0.,0.,0.,0.}, a2 = {0.,0.,0.,0.}, a3 = {0.,0.,0.,0.};
  const float* wp = W + (size_t)sub * VSZ + colA;
  float aC = wp[0]; wp += (size_t)4 * VSZ;
  float aN = wp[0]; wp += (size_t)4 * VSZ;
  for (int ch = 0; ch < 16; ++ch) {
    __syncthreads();
    const double2* src = (const double2*)(h1T + (size_t)ch * 64 * 64);
    double2* dst = (double2*)xs;
    for (int i = tid; i < 2048; i += 256) dst[i] = src[i];
    __syncthreads();
    for (int ks = 0; ks < 16; ++ks) {
      int gks = ch * 16 + ks;
      float aP = 0.f;
      if (gks + 2 < 256) aP = wp[0];
      wp += (size_t)4 * VSZ;
      double av = (double)aC;
      const double* bp = xs + (ks * 4 + sub) * 64 + lane16;
      double b0 = bp[0], b1 = bp[16], b2 = bp[32], b3 = bp[48];
      a0 = __builtin_amdgcn_mfma_f64_16x16x4f64(av, b0, a0, 0, 0, 0);
      a1 = __builtin_amdgcn_mfma_f64_16x16x4f64(av, b1, a1, 0, 0, 0);
      a2 = __builtin_amdgcn_mfma_f64_16x16x4f64(av, b2, a2, 0, 0, 0);
      a3 = __builtin_amdgcn_mfma_f64_16x16x4f64(av, b3, a3, 0, 0, 0);
      aC = aN; aN = aP;
    }
  }
  // verify D(v=vbase+1, b=0) and D(v=vbase+1, b=48); vbase+1 <= 50241 < VSZ always
  if (wv == 0) {
    double r0 = 0.0, r48 = 0.0;
#pragma unroll
    for (int q = 0; q < 16; ++q) {
      int k = q * 64 + l;
      double wvv = (double)W[(size_t)k * VSZ + vbase + 1];
      r0  += wvv * h1T[(size_t)k * 64];
      r48 += wvv * h1T[(size_t)k * 64 + 48];
    }
#pragma unroll
    for (int off = 1; off < 64; off <<= 1) {
      r0  += __shfl_xor(r0, off, 64);
      r48 += __shfl_xor(r48, off, 64);
    }
    int lsel = (conv == 0) ? 0 : (conv == 2) ? 16 : 1;
    int rsel = (conv == 0) ? 1 : 0;
    double g0a = __shfl(a0[0], lsel, 64), g0b = __shfl(a0[1], lsel, 64);
    double g3a = __shfl(a3[0], lsel, 64), g3b = __shfl(a3[1], lsel, 64);
    double got0  = rsel ? g0b : g0a;
    double got48 = rsel ? g3b : g3a;
    bool ok = (fabs(got0 - r0)   <= 1e-9 * (1.0 + fabs(r0))) &&
              (fabs(got48 - r48) <= 1e-9 * (1.0 + fabs(r48)));
    if (l == 0) { okS = ok ? 1 : 0; if (!ok) atomicOr(fbw, 1); }
  }
  __syncthreads();   // covers: last B-reads of xs done, okS visible
  if (!okS) return;  // uniform; fallback k_fctop_fb redoes this block's candidates
  // bias + /TEMP, swizzled transpose into xs[b][(vl+b)&63]
#pragma unroll
  for (int j = 0; j < 4; ++j) {
    int m = (conv == 0) ? sub * 4 + j : (conv == 2) ? sub + 4 * j : lane16;
    int n = (conv == 0) ? lane16 : (conv == 2) ? lane16 : ((conv == 1) ? sub * 4 + j : sub + 4 * j);
    int vl = wv * 16 + m;
    int v = vbase + vl;
    bool okv = (v < VSZ);
    double bi = okv ? (double)fcb[min(v, VSZ - 1)] : 0.0;
    int b0i = n, b1i = 16 + n, b2i = 32 + n, b3i = 48 + n;
    xs[b0i * 64 + ((vl + b0i) & 63)] = okv ? (a0[j] + bi) / 0.75 : -INFINITY;
    xs[b1i * 64 + ((vl + b1i) & 63)] = okv ? (a1[j] + bi) / 0.75 : -INFINITY;
    xs[b2i * 64 + ((vl + b2i) & 63)] = okv ? (a2[j] + bi) / 0.75 : -INFINITY;
    xs[b3i * 64 + ((vl + b3i) & 63)] = okv ? (a3[j] + bi) / 0.75 : -INFINITY;
  }
  __syncthreads();
  if (tid < 64) {
    int b = tid;
    double tv[5]; int ti[5];
#pragma unroll
    for (int p = 0; p < 5; ++p) { tv[p] = -INFINITY; ti[p] = INT_MAX; }
    for (int vl2 = 0; vl2 < 64; ++vl2)
      ins5(xs[b * 64 + ((vl2 + b) & 63)], vbase + vl2, tv, ti);
#pragma unroll
    for (int r = 0; r < 5; ++r) {
      candV[(size_t)b * NCAND + blockIdx.x * 5 + r] = tv[r];
      candI[(size_t)b * NCAND + blockIdx.x * 5 + r] = ti[r];
    }
  }
}

// ================= Fallback path (bit-exact R4 kernels, guarded) =================

#define FMABLK(W0V, W1V, KIDX)                                                        \
  {                                                                                   \
    double w0 = (double)(W0V), w1 = (double)(W1V);                                    \
    const double2* xp = (const double2*)xs + ((KIDX) << 5) + (bg << 2);               \
    double2 xa = xp[0], xb = xp[1], xc = xp[2], xd = xp[3];                           \
    acc[0][0] = fma(w0, xa.x, acc[0][0]); acc[0][1] = fma(w0, xa.y, acc[0][1]);       \
    acc[0][2] = fma(w0, xb.x, acc[0][2]); acc[0][3] = fma(w0, xb.y, acc[0][3]);       \
    acc[0][4] = fma(w0, xc.x, acc[0][4]); acc[0][5] = fma(w0, xc.y, acc[0][5]);       \
    acc[0][6] = fma(w0, xd.x, acc[0][6]); acc[0][7] = fma(w0, xd.y, acc[0][7]);       \
    acc[1][0] = fma(w1, xa.x, acc[1][0]); acc[1][1] = fma(w1, xa.y, acc[1][1]);       \
    acc[1][2] = fma(w1, xb.x, acc[1][2]); acc[1][3] = fma(w1, xb.y, acc[1][3]);       \
    acc[1][4] = fma(w1, xc.x, acc[1][4]); acc[1][5] = fma(w1, xc.y, acc[1][5]);       \
    acc[1][6] = fma(w1, xd.x, acc[1][6]); acc[1][7] = fma(w1, xd.y, acc[1][7]);       \
  }

__global__ __launch_bounds__(256, 4) void k_lstm_fb(const double* __restrict__ x0, const float* __restrict__ W0,
                                                    const double* __restrict__ x1, const float* __restrict__ W1,
                                                    const double* __restrict__ x2, const float* __restrict__ W2,
                                                    int s1, int s2, double* __restrict__ part,
                                                    const int* __restrict__ fb) {
  if (fb[0] < 4 && fb[1] == 0) return;   // MFMA path succeeded
  __shared__ double xs[64 * 64];
  int tid = threadIdx.x;
  int vg = tid & 31, bg = tid >> 5;
  int colbase = blockIdx.x * 64;
  int s = blockIdx.y;
  const double* XT; const float* W; int k0;
  if (s < s1)      { XT = x0; W = W0; k0 = s * 128; }
  else if (s < s2) { XT = x1; W = W1; k0 = (s - s1) * 128; }
  else             { XT = x2; W = W2; k0 = (s - s2) * 128; }
  double acc[2][8];
#pragma unroll
  for (int i = 0; i < 2; ++i)
#pragma unroll
    for (int j = 0; j < 8; ++j) acc[i][j] = 0.0;
  float w0b[8], w1b[8];
  for (int ch = 0; ch < 2; ++ch) {
    const float* wr = W + (size_t)(k0 + ch * 64) * GC + colbase + vg;
#pragma unroll
    for (int u = 0; u < 8; ++u) { w0b[u] = wr[0]; w1b[u] = wr[32]; wr += GC; }
    __syncthreads();
    const double2* src = (const double2*)(XT + (size_t)(k0 + ch * 64) * 64);
    double2* dst = (double2*)xs;
    for (int i = tid; i < 2048; i += 256) dst[i] = src[i];
    __syncthreads();
    for (int kk = 0; kk < 56; kk += 8) {
#pragma unroll
      for (int u = 0; u < 8; ++u) {
        float nw0 = wr[0], nw1 = wr[32]; wr += GC;
        FMABLK(w0b[u], w1b[u], kk + u)
        w0b[u] = nw0; w1b[u] = nw1;
      }
    }
#pragma unroll
    for (int u = 0; u < 8; ++u) { FMABLK(w0b[u], w1b[u], 56 + u) }
  }
#pragma unroll
  for (int j = 0; j < 8; ++j) {
    int b = bg * 8 + j;
    double* o = part + ((size_t)s * 64 + b) * GC + colbase + vg;
    o[0]  = acc[0][j];
    o[32] = acc[1][j];
  }
}

__global__ __launch_bounds__(256, 4) void k_fctop_fb(const double* __restrict__ h1T, const float* __restrict__ W,
                                                     const float* __restrict__ fcb,
                                                     double* __restrict__ candV, int* __restrict__ candI,
                                                     const int* __restrict__ fb) {
  if (fb[0] < 4 && fb[1] == 0) return;   // MFMA path succeeded
  __shared__ double xs[64 * 64];
  int tid = threadIdx.x;
  int vg = tid & 31, bg = tid >> 5;
  int vbase = blockIdx.x * 64;
  int c0 = min(vbase + vg,      VSZ - 1);
  int c1 = min(vbase + vg + 32, VSZ - 1);
  double acc[2][8];
#pragma unroll
  for (int i = 0; i < 2; ++i)
#pragma unroll
    for (int j = 0; j < 8; ++j) acc[i][j] = 0.0;
  float w0b[8], w1b[8];
  for (int ch = 0; ch < 16; ++ch) {
    const float* wr = W + (size_t)(ch * 64) * VSZ;
#pragma unroll
    for (int u = 0; u < 8; ++u) { w0b[u] = wr[c0]; w1b[u] = wr[c1]; wr += VSZ; }
    __syncthreads();
    const double2* src = (const double2*)(h1T + (size_t)ch * 64 * 64);
    double2* dst = (double2*)xs;
    for (int i = tid; i < 2048; i += 256) dst[i] = src[i];
    __syncthreads();
    for (int kk = 0; kk < 56; kk += 8) {
#pragma unroll
      for (int u = 0; u < 8; ++u) {
        float nw0 = wr[c0], nw1 = wr[c1]; wr += VSZ;
        FMABLK(w0b[u], w1b[u], kk + u)
        w0b[u] = nw0; w1b[u] = nw1;
      }
    }
#pragma unroll
    for (int u = 0; u < 8; ++u) { FMABLK(w0b[u], w1b[u], 56 + u) }
  }
  __syncthreads();
#pragma unroll
  for (int i = 0; i < 2; ++i) {
    int v = vbase + vg + 32 * i;
    bool ok = (v < VSZ);
    double bi = ok ? (double)fcb[min(v, VSZ - 1)] : 0.0;
    int vl = vg + 32 * i;
#pragma unroll
    for (int j = 0; j < 8; ++j) {
      int b = bg * 8 + j;
      double val = ok ? (acc[i][j] + bi) / 0.75 : -INFINITY;
      xs[b * 64 + ((vl + b) & 63)] = val;
    }
  }
  __syncthreads();
  if (tid < 64) {
    int b = tid;
    double tv[5]; int ti[5];
#pragma unroll
    for (int p = 0; p < 5; ++p) { tv[p] = -INFINITY; ti[p] = INT_MAX; }
    for (int vl = 0; vl < 64; ++vl)
      ins5(xs[b * 64 + ((vl + b) & 63)], vbase + vl, tv, ti);
#pragma unroll
    for (int r = 0; r < 5; ++r) {
      candV[(size_t)b * NCAND + blockIdx.x * 5 + r] = tv[r];
      candI[(size_t)b * NCAND + blockIdx.x * 5 + r] = ti[r];
    }
  }
}

// -------- LSTM cell: sum partial slots [sBeg, sBeg+S) + bias; gates i,f,g,o --------
__global__ __launch_bounds__(256) void k_cell(const double* __restrict__ part, int sBeg, int S,
                                              const float* __restrict__ bias,
                                              double* __restrict__ c, double* __restrict__ hT) {
  int b = blockIdx.y;
  int hcol = blockIdx.x * 256 + threadIdx.x;
  double gi = (double)bias[hcol];
  double gf = (double)bias[1024 + hcol];
  double gg = (double)bias[2048 + hcol];
  double go = (double)bias[3072 + hcol];
#pragma unroll 4
  for (int s = sBeg; s < sBeg + S; ++s) {
    const double* p = part + ((size_t)s * 64 + b) * GC;
    gi += p[hcol]; gf += p[1024 + hcol]; gg += p[2048 + hcol]; go += p[3072 + hcol];
  }
  size_t ci = (size_t)b * HSZ + hcol;
  double cn = dsig(gf) * c[ci] + dsig(gi) * tanh(gg);
  double hn = dsig(go) * tanh(cn);
  c[ci] = cn;
  hT[(size_t)hcol * 64 + b] = hn;
}

// -------- final merge (3930 cands, b-major) + gumbel sample + outputs --------
__global__ __launch_bounds__(64) void k_fin(const double* __restrict__ candV, const int* __restrict__ candI,
                                            const double* __restrict__ gum, int t,
                                            const float* __restrict__ embed,
                                            float* __restrict__ out, double* __restrict__ xt0) {
  int b = blockIdx.x, lane = threadIdx.x;
  double tv[5]; int ti[5];
#pragma unroll
  for (int p = 0; p < 5; ++p) { tv[p] = -INFINITY; ti[p] = INT_MAX; }
  const double* cv = candV + (size_t)b * NCAND;
  const int*    ci = candI + (size_t)b * NCAND;
  for (int e = lane; e < NCAND; e += 64)
    ins5(cv[e], ci[e], tv, ti);
  double mv[5]; int mi[5];
#pragma unroll
  for (int r = 0; r < 5; ++r) {
    double bv = tv[0]; int bi = ti[0];
    for (int off = 1; off < 64; off <<= 1) {
      double ov = __shfl_xor(bv, off, 64);
      int oi = __shfl_xor(bi, off, 64);
      if (ov > bv || (ov == bv && oi < bi)) { bv = ov; bi = oi; }
    }
    mv[r] = bv; mi[r] = bi;
    if (tv[0] == bv && ti[0] == bi) {
#pragma unroll
      for (int p = 0; p < 4; ++p) { tv[p] = tv[p+1]; ti[p] = ti[p+1]; }
      tv[4] = -INFINITY; ti[4] = INT_MAX;
    }
  }
  const double* g = gum + (size_t)t * 320 + b * 5;
  double bestv = mv[0] + g[0]; int best = 0;
#pragma unroll
  for (int k2 = 1; k2 < 5; ++k2) { double vv = mv[k2] + g[k2]; if (vv > bestv) { bestv = vv; best = k2; } }
  int nxt = mi[best];
  if (lane == 0) {
    out[b * TSZ + t] = (float)nxt;
    double m = mv[0];
    double ex[5]; double s = 0.0;
#pragma unroll
    for (int k2 = 0; k2 < 5; ++k2) { ex[k2] = exp(mv[k2] - m); s += ex[k2]; }
    float* po = out + BSZ * TSZ + ((size_t)b * TSZ + t) * 5;
#pragma unroll
    for (int k2 = 0; k2 < 5; ++k2) po[k2] = (float)(ex[k2] / s);
  }
  for (int k = lane; k < ESZ; k += 64)
    xt0[(size_t)k * 64 + b] = (double)embed[(size_t)nxt * ESZ + k];
}

// -------- initial embedding of SOS --------
__global__ __launch_bounds__(256) void k_emb0(const float* __restrict__ embed, const int* __restrict__ sos,
                                              double* __restrict__ xt0) {
  int idx = blockIdx.x * 256 + threadIdx.x;
  int b = idx & 63, k = idx >> 6;
  xt0[(size_t)k * 64 + b] = (double)embed[(size_t)sos[0] * ESZ + k];
}

extern "C" void kernel_launch(void* const* d_in, const int* in_sizes, int n_in,
                              void* d_out, int out_size, void* d_ws, size_t ws_size,
                              hipStream_t stream) {
  const float* hours = (const float*)d_in[0];
  const float* tp_w1 = (const float*)d_in[1];
  const float* tp_b1 = (const float*)d_in[2];
  const float* tp_w2 = (const float*)d_in[3];
  const float* tp_b2 = (const float*)d_in[4];
  const float* embed = (const float*)d_in[5];
  const float* w_ih0 = (const float*)d_in[6];
  const float* w_hh0 = (const float*)d_in[7];
  const float* b0    = (const float*)d_in[8];
  const float* w_ih1 = (const float*)d_in[9];
  const float* w_hh1 = (const float*)d_in[10];
  const float* b1    = (const float*)d_in[11];
  const float* fc_w  = (const float*)d_in[12];
  const float* fc_b  = (const float*)d_in[13];
  const int*   sos   = (const int*)d_in[14];
  float* out = (float*)d_out;

  char* w = (char*)d_ws;
  double* part = (double*)w;  w += (size_t)NSLOT * 64 * GC * 8;   // 54.5 MB lstm partials
  double* xt0  = (double*)w;  w += (size_t)ESZ * 64 * 8;
  double* h0T  = (double*)w;  w += (size_t)HSZ * 64 * 8;
  double* h1T  = (double*)w;  w += (size_t)HSZ * 64 * 8;
  double* c0   = (double*)w;  w += (size_t)BSZ * HSZ * 8;
  double* c1   = (double*)w;  w += (size_t)BSZ * HSZ * 8;
  double* tp1T = (double*)w;  w += (size_t)HSZ * 64 * 8;
  double* gum  = (double*)w;  w += (size_t)TSZ * 320 * 8;
  double* candV = (double*)w; w += (size_t)BSZ * NCAND * 8;       // 2.01 MB, b-major
  int*    candI = (int*)w;    w += (size_t)BSZ * NCAND * 4;       // 1.01 MB
  int*    fbuf  = (int*)w;    w += 64;                            // [0]=conv, [1]=bad

  k_probe<<<dim3(1), dim3(64), 0, stream>>>(fbuf);
  k_rng<<<dim3(100), dim3(256), 0, stream>>>(gum);
  k_time1<<<dim3(256), dim3(256), 0, stream>>>(hours, tp_w1, tp_b1, tp1T);
  k_gemm_simple<<<dim3(16, 8), dim3(256), 0, stream>>>(tp1T, tp_w2, 1024, 8, part);
  k_t2r<<<dim3(16, 64), dim3(256), 0, stream>>>(part, tp_b2, h0T, c0, h1T, c1);
  k_emb0<<<dim3(64), dim3(256), 0, stream>>>(embed, sos, xt0);

  double* part18 = part + (size_t)18 * 64 * GC;
  for (int t = 0; t < TSZ; ++t) {
    // A: slices 0-1 = xt0*w_ih0, 2-9 = h0*w_hh0, 10-17 = h1*w_hh1 -> slots 0..17
    k_lstm_mfma<<<dim3(64, 18), dim3(256), 0, stream>>>(xt0, w_ih0, h0T, w_hh0, h1T, w_hh1, 2, 10, part, fbuf, fbuf + 1);
    k_lstm_fb<<<dim3(64, 18), dim3(256), 0, stream>>>(xt0, w_ih0, h0T, w_hh0, h1T, w_hh1, 2, 10, part, fbuf);
    k_cell<<<dim3(4, 64), dim3(256), 0, stream>>>(part, 0, 10, b0, c0, h0T);
    // B: slices 0-7 = h0n*w_ih1 -> slots 18..25
    k_lstm_mfma<<<dim3(64, 8), dim3(256), 0, stream>>>(h0T, w_ih1, h0T, w_ih1, h0T, w_ih1, 8, 8, part18, fbuf, fbuf + 1);
    k_lstm_fb<<<dim3(64, 8), dim3(256), 0, stream>>>(h0T, w_ih1, h0T, w_ih1, h0T, w_ih1, 8, 8, part18, fbuf);
    k_cell<<<dim3(4, 64), dim3(256), 0, stream>>>(part, 10, 16, b1, c1, h1T);
    k_fcmfma<<<dim3(NFCB), dim3(256), 0, stream>>>(h1T, fc_w, fc_b, candV, candI, fbuf, fbuf + 1);
    k_fctop_fb<<<dim3(NFCB), dim3(256), 0, stream>>>(h1T, fc_w, fc_b, candV, candI, fbuf);
    k_fin<<<dim3(64), dim3(64), 0, stream>>>(candV, candI, gum, t, embed, out, xt0);
  }
}

// Round 9
// 24295.610 us; speedup vs baseline: 1.4442x; 1.0737x over previous
//
#include <hip/hip_runtime.h>
#include <math.h>
#include <stdint.h>
#include <limits.h>

#define VSZ 50257
#define ESZ 256
#define HSZ 1024
#define BSZ 64
#define TSZ 80
#define GC  4096            // 4*H gate columns
#define NFCB 786            // ceil(VSZ/64) FC col-blocks
#define NCAND (NFCB*5)      // 3930 candidates per batch row
#define NSLOT 26            // lstm part slots: A 0..17, B 18..25

typedef unsigned int u32;
typedef double f64x4 __attribute__((ext_vector_type(4)));

// ---------------- Threefry-2x32 (JAX exact) ----------------
__device__ __forceinline__ void tf2x32(u32 k0, u32 k1, u32& x0, u32& x1) {
  u32 ks2 = k0 ^ k1 ^ 0x1BD11BDAu;
  x0 += k0; x1 += k1;
#define RND(r) { x0 += x1; x1 = (x1 << r) | (x1 >> (32 - r)); x1 ^= x0; }
  RND(13) RND(15) RND(26) RND(6)
  x0 += k1; x1 += ks2 + 1u;
  RND(17) RND(29) RND(16) RND(24)
  x0 += ks2; x1 += k0 + 2u;
  RND(13) RND(15) RND(26) RND(6)
  x0 += k0; x1 += k1 + 3u;
  RND(17) RND(29) RND(16) RND(24)
  x0 += k1; x1 += ks2 + 4u;
  RND(13) RND(15) RND(26) RND(6)
  x0 += ks2; x1 += k0 + 5u;
#undef RND
}

__device__ __forceinline__ double dsig(double x) { return 0.5 + 0.5 * tanh(0.5 * x); }

// sorted-desc top5 insert; ties -> lower index first (matches lax.top_k)
__device__ __forceinline__ void ins5(double v, int i, double* tv, int* ti) {
  bool beat4 = (v > tv[4]) || (v == tv[4] && i < ti[4]);
  if (!beat4) return;
  tv[4] = v; ti[4] = i;
#pragma unroll
  for (int p = 4; p > 0; --p) {
    bool sw = (tv[p] > tv[p-1]) || (tv[p] == tv[p-1] && ti[p] < ti[p-1]);
    double a0 = sw ? tv[p] : tv[p-1]; double a1 = sw ? tv[p-1] : tv[p];
    tv[p-1] = a0; tv[p] = a1;
    int b0 = sw ? ti[p] : ti[p-1]; int b1 = sw ? ti[p-1] : ti[p];
    ti[p-1] = b0; ti[p] = b1;
  }
}

// exact integer reference D[m][n] for the probe: sum_k (4m+k+1)*(16k+n+1)
__device__ __forceinline__ double dref(int m, int n) {
  int s = 0;
#pragma unroll
  for (int k = 0; k < 4; ++k) s += (4*m + k + 1) * (16*k + n + 1);
  return (double)s;
}

// -------- MFMA layout probe: fb[0] = conv index (0..3) --------
// conv0: D[4*sub+j][lane16]  conv1: D[lane16][4*sub+j]
// conv2: D[sub+4*j][lane16]  conv3: D[lane16][sub+4*j]
// R8 validated on-HW: probe-selected conv + these epilogues give absmax 0.0 end-to-end.
__global__ __launch_bounds__(64) void k_probe(int* __restrict__ fb) {
  int l = threadIdx.x;
  int lane16 = l & 15, sub = l >> 4;
  double av = (double)(4 * lane16 + sub + 1);     // A[m=lane16][k=sub]
  double bv = (double)(16 * sub + lane16 + 1);    // B[k=sub][n=lane16]
  f64x4 acc = {0., 0., 0., 0.};
  acc = __builtin_amdgcn_mfma_f64_16x16x4f64(av, bv, acc, 0, 0, 0);
  bool o0 = true, o1 = true, o2 = true, o3 = true;
#pragma unroll
  for (int j = 0; j < 4; ++j) {
    double d = acc[j];
    o0 = o0 && (d == dref(4 * sub + j, lane16));
    o1 = o1 && (d == dref(lane16, 4 * sub + j));
    o2 = o2 && (d == dref(sub + 4 * j, lane16));
    o3 = o3 && (d == dref(lane16, sub + 4 * j));
  }
  int a0 = __all(o0), a1 = __all(o1), a2 = __all(o2), a3 = __all(o3);
  if (l == 0) fb[0] = a0 ? 0 : a1 ? 1 : a2 ? 2 : 3;
}

// -------- fused RNG: gumbel[t][m] for t<80, m<320 --------
__global__ __launch_bounds__(256) void k_rng(double* __restrict__ gum) {
  int idx = blockIdx.x * 256 + threadIdx.x;
  if (idx >= TSZ * 320) return;
  int t = idx / 320, m = idx % 320;
  u32 a0 = 0u, a1 = (u32)t;
  tf2x32(0u, 42u, a0, a1);
  u32 x0 = 0u, x1 = (u32)m;
  tf2x32(a0, a1, x0, x1);
  u32 bits = x0 ^ x1;
  const float TINY = 1.17549435082228750797e-38f;  // 2^-126
  float f = __uint_as_float((bits >> 9) | 0x3f800000u) - 1.0f;
  float u = f + TINY;
  u = fmaxf(TINY, u);
  gum[idx] = -log(-log((double)u));
}

// -------- time encode stage 1 --------
__global__ __launch_bounds__(256) void k_time1(const float* __restrict__ hours, const float* __restrict__ w1,
                                               const float* __restrict__ bb1, double* __restrict__ tp1T) {
  int idx = blockIdx.x * 256 + threadIdx.x;  // 64*1024
  int b = idx & 63, hcol = idx >> 6;
  const float TPO = (float)(2.0 * 3.14159265358979323846 / 24.0);
  float af = hours[b] * TPO;
  double a = (double)af;
  double sv = sin(a), cv = cos(a);
  double vv = tanh(sv * (double)w1[hcol] + cv * (double)w1[HSZ + hcol] + (double)bb1[hcol]);
  tp1T[(size_t)hcol * 64 + b] = vv;
}

// -------- simple split-K gemm (prologue-only, runs once) --------
__global__ __launch_bounds__(256) void k_gemm_simple(const double* __restrict__ XTa, const float* __restrict__ Wa,
                                                     int Ka, int Sa, double* __restrict__ part) {
  int j = blockIdx.x * 256 + threadIdx.x;
  if (j >= GC) return;
  int s = blockIdx.y;
  int kc = Ka / Sa, k0 = s * kc;
  double acc[BSZ];
#pragma unroll
  for (int b = 0; b < BSZ; ++b) acc[b] = 0.0;
  const float* wp = Wa + (size_t)k0 * GC + j;
  const double* xp = XTa + (size_t)k0 * 64;
  for (int k = 0; k < kc; ++k) {
    double wv = (double)wp[0]; wp += GC;
#pragma unroll
    for (int b = 0; b < BSZ; ++b) acc[b] = fma(wv, xp[b], acc[b]);
    xp += 64;
  }
  double* o = part + ((size_t)s * 64) * GC + j;
#pragma unroll
  for (int b = 0; b < BSZ; ++b) o[(size_t)b * GC] = acc[b];
}

// -------- time encode stage 2 reduce --------
__global__ __launch_bounds__(256) void k_t2r(const double* __restrict__ part, const float* __restrict__ b2,
                                             double* __restrict__ h0T, double* __restrict__ c0,
                                             double* __restrict__ h1T, double* __restrict__ c1) {
  int b = blockIdx.y;
  int j = blockIdx.x * 256 + threadIdx.x;
  double acc = (double)b2[j];
  for (int s = 0; s < 8; ++s) acc += part[((size_t)s * 64 + b) * GC + j];
  int l = j >> 11, half = (j >> 10) & 1, hcol = j & 1023;
  if (half == 0) (l ? h1T : h0T)[(size_t)hcol * 64 + b] = acc;
  else           (l ? c1 : c0)[(size_t)b * HSZ + hcol] = acc;
}

// -------- LSTM gemm via f64 MFMA; conv-parameterized D write; part[s][b][col] --------
__global__ __launch_bounds__(256, 4) void k_lstm_mfma(const double* __restrict__ x0, const float* __restrict__ W0,
                                                      const double* __restrict__ x1, const float* __restrict__ W1,
                                                      const double* __restrict__ x2, const float* __restrict__ W2,
                                                      int s1, int s2, double* __restrict__ part,
                                                      const int* __restrict__ fb) {
  int conv = fb[0] & 3;
  __shared__ double xs[64 * 64];   // 32KB x-chunk [k][b]
  int tid = threadIdx.x;
  int l = tid & 63, wv = tid >> 6;
  int sub = l >> 4, lane16 = l & 15;
  int colbase = blockIdx.x * 64;
  int s = blockIdx.y;
  const double* XT; const float* W; int k0;
  if (s < s1)      { XT = x0; W = W0; k0 = s * 128; }
  else if (s < s2) { XT = x1; W = W1; k0 = (s - s1) * 128; }
  else             { XT = x2; W = W2; k0 = (s - s2) * 128; }
  int colA = colbase + wv * 16 + lane16;
  f64x4 a0 = {0.,0.,0.,0.}, a1 = {0.,0.,0.,0.}, a2 = {0.,0.,0.,0.}, a3 = {0.,0.,0.,0.};
  const float* wp = W + (size_t)(k0 + sub) * GC + colA;
  float aC = wp[0]; wp += (size_t)4 * GC;
  float aN = wp[0]; wp += (size_t)4 * GC;
  for (int ch = 0; ch < 2; ++ch) {
    __syncthreads();
    const double2* src = (const double2*)(XT + (size_t)(k0 + ch * 64) * 64);
    double2* dst = (double2*)xs;
    for (int i = tid; i < 2048; i += 256) dst[i] = src[i];
    __syncthreads();
    for (int ks = 0; ks < 16; ++ks) {
      int gks = ch * 16 + ks;
      float aP = 0.f;
      if (gks + 2 < 32) aP = wp[0];
      wp += (size_t)4 * GC;
      double av = (double)aC;
      const double* bp = xs + (ks * 4 + sub) * 64 + lane16;
      double b0 = bp[0], b1 = bp[16], b2 = bp[32], b3 = bp[48];
      a0 = __builtin_amdgcn_mfma_f64_16x16x4f64(av, b0, a0, 0, 0, 0);
      a1 = __builtin_amdgcn_mfma_f64_16x16x4f64(av, b1, a1, 0, 0, 0);
      a2 = __builtin_amdgcn_mfma_f64_16x16x4f64(av, b2, a2, 0, 0, 0);
      a3 = __builtin_amdgcn_mfma_f64_16x16x4f64(av, b3, a3, 0, 0, 0);
      aC = aN; aN = aP;
    }
  }
#pragma unroll
  for (int j = 0; j < 4; ++j) {
    int m = (conv == 0) ? sub * 4 + j : (conv == 2) ? sub + 4 * j : lane16;
    int n = (conv == 0) ? lane16 : (conv == 2) ? lane16 : ((conv == 1) ? sub * 4 + j : sub + 4 * j);
    size_t base = ((size_t)s * 64 + n) * GC + colbase + wv * 16 + m;
    part[base]                   = a0[j];
    part[base + (size_t)16 * GC] = a1[j];
    part[base + (size_t)32 * GC] = a2[j];
    part[base + (size_t)48 * GC] = a3[j];
  }
}

// -------- LSTM cell: sum partial slots [sBeg, sBeg+S) + bias; gates i,f,g,o --------
__global__ __launch_bounds__(256) void k_cell(const double* __restrict__ part, int sBeg, int S,
                                              const float* __restrict__ bias,
                                              double* __restrict__ c, double* __restrict__ hT) {
  int b = blockIdx.y;
  int hcol = blockIdx.x * 256 + threadIdx.x;
  double gi = (double)bias[hcol];
  double gf = (double)bias[1024 + hcol];
  double gg = (double)bias[2048 + hcol];
  double go = (double)bias[3072 + hcol];
#pragma unroll 4
  for (int s = sBeg; s < sBeg + S; ++s) {
    const double* p = part + ((size_t)s * 64 + b) * GC;
    gi += p[hcol]; gf += p[1024 + hcol]; gg += p[2048 + hcol]; go += p[3072 + hcol];
  }
  size_t ci = (size_t)b * HSZ + hcol;
  double cn = dsig(gf) * c[ci] + dsig(gi) * tanh(gg);
  double hn = dsig(go) * tanh(cn);
  c[ci] = cn;
  hT[(size_t)hcol * 64 + b] = hn;
}

// -------- FC via f64 MFMA + fused top5; conv-parameterized --------
__global__ __launch_bounds__(256, 4) void k_fcmfma(const double* __restrict__ h1T, const float* __restrict__ W,
                                                   const float* __restrict__ fcb,
                                                   double* __restrict__ candV, int* __restrict__ candI,
                                                   const int* __restrict__ fb) {
  int conv = fb[0] & 3;
  __shared__ double xs[64 * 64];   // x-chunk staging, then transpose buffer
  int tid = threadIdx.x;
  int l = tid & 63, wv = tid >> 6;
  int sub = l >> 4, lane16 = l & 15;
  int vbase = blockIdx.x * 64;
  int colA = min(vbase + wv * 16 + lane16, VSZ - 1);
  f64x4 a0 = {0.,0.,0.,0.}, a1 = {0.,0.,0.,0.}, a2 = {0.,0.,0.,0.}, a3 = {0.,0.,0.,0.};
  const float* wp = W + (size_t)sub * VSZ + colA;
  float aC = wp[0]; wp += (size_t)4 * VSZ;
  float aN = wp[0]; wp += (size_t)4 * VSZ;
  for (int ch = 0; ch < 16; ++ch) {
    __syncthreads();
    const double2* src = (const double2*)(h1T + (size_t)ch * 64 * 64);
    double2* dst = (double2*)xs;
    for (int i = tid; i < 2048; i += 256) dst[i] = src[i];
    __syncthreads();
    for (int ks = 0; ks < 16; ++ks) {
      int gks = ch * 16 + ks;
      float aP = 0.f;
      if (gks + 2 < 256) aP = wp[0];
      wp += (size_t)4 * VSZ;
      double av = (double)aC;
      const double* bp = xs + (ks * 4 + sub) * 64 + lane16;
      double b0 = bp[0], b1 = bp[16], b2 = bp[32], b3 = bp[48];
      a0 = __builtin_amdgcn_mfma_f64_16x16x4f64(av, b0, a0, 0, 0, 0);
      a1 = __builtin_amdgcn_mfma_f64_16x16x4f64(av, b1, a1, 0, 0, 0);
      a2 = __builtin_amdgcn_mfma_f64_16x16x4f64(av, b2, a2, 0, 0, 0);
      a3 = __builtin_amdgcn_mfma_f64_16x16x4f64(av, b3, a3, 0, 0, 0);
      aC = aN; aN = aP;
    }
  }
  __syncthreads();   // last B-reads of xs done; reuse as transpose buffer
  // bias + /TEMP, swizzled transpose into xs[b][(vl+b)&63]
#pragma unroll
  for (int j = 0; j < 4; ++j) {
    int m = (conv == 0) ? sub * 4 + j : (conv == 2) ? sub + 4 * j : lane16;
    int n = (conv == 0) ? lane16 : (conv == 2) ? lane16 : ((conv == 1) ? sub * 4 + j : sub + 4 * j);
    int vl = wv * 16 + m;
    int v = vbase + vl;
    bool okv = (v < VSZ);
    double bi = okv ? (double)fcb[min(v, VSZ - 1)] : 0.0;
    int b0i = n, b1i = 16 + n, b2i = 32 + n, b3i = 48 + n;
    xs[b0i * 64 + ((vl + b0i) & 63)] = okv ? (a0[j] + bi) / 0.75 : -INFINITY;
    xs[b1i * 64 + ((vl + b1i) & 63)] = okv ? (a1[j] + bi) / 0.75 : -INFINITY;
    xs[b2i * 64 + ((vl + b2i) & 63)] = okv ? (a2[j] + bi) / 0.75 : -INFINITY;
    xs[b3i * 64 + ((vl + b3i) & 63)] = okv ? (a3[j] + bi) / 0.75 : -INFINITY;
  }
  __syncthreads();
  if (tid < 64) {
    int b = tid;
    double tv[5]; int ti[5];
#pragma unroll
    for (int p = 0; p < 5; ++p) { tv[p] = -INFINITY; ti[p] = INT_MAX; }
    for (int vl2 = 0; vl2 < 64; ++vl2)
      ins5(xs[b * 64 + ((vl2 + b) & 63)], vbase + vl2, tv, ti);
#pragma unroll
    for (int r = 0; r < 5; ++r) {
      candV[(size_t)b * NCAND + blockIdx.x * 5 + r] = tv[r];
      candI[(size_t)b * NCAND + blockIdx.x * 5 + r] = ti[r];
    }
  }
}

// -------- final merge (3930 cands, b-major) + gumbel sample + outputs --------
__global__ __launch_bounds__(64) void k_fin(const double* __restrict__ candV, const int* __restrict__ candI,
                                            const double* __restrict__ gum, int t,
                                            const float* __restrict__ embed,
                                            float* __restrict__ out, double* __restrict__ xt0) {
  int b = blockIdx.x, lane = threadIdx.x;
  double tv[5]; int ti[5];
#pragma unroll
  for (int p = 0; p < 5; ++p) { tv[p] = -INFINITY; ti[p] = INT_MAX; }
  const double* cv = candV + (size_t)b * NCAND;
  const int*    ci = candI + (size_t)b * NCAND;
  for (int e = lane; e < NCAND; e += 64)
    ins5(cv[e], ci[e], tv, ti);
  double mv[5]; int mi[5];
#pragma unroll
  for (int r = 0; r < 5; ++r) {
    double bv = tv[0]; int bi = ti[0];
    for (int off = 1; off < 64; off <<= 1) {
      double ov = __shfl_xor(bv, off, 64);
      int oi = __shfl_xor(bi, off, 64);
      if (ov > bv || (ov == bv && oi < bi)) { bv = ov; bi = oi; }
    }
    mv[r] = bv; mi[r] = bi;
    if (tv[0] == bv && ti[0] == bi) {
#pragma unroll
      for (int p = 0; p < 4; ++p) { tv[p] = tv[p+1]; ti[p] = ti[p+1]; }
      tv[4] = -INFINITY; ti[4] = INT_MAX;
    }
  }
  const double* g = gum + (size_t)t * 320 + b * 5;
  double bestv = mv[0] + g[0]; int best = 0;
#pragma unroll
  for (int k2 = 1; k2 < 5; ++k2) { double vv = mv[k2] + g[k2]; if (vv > bestv) { bestv = vv; best = k2; } }
  int nxt = mi[best];
  if (lane == 0) {
    out[b * TSZ + t] = (float)nxt;
    double m = mv[0];
    double ex[5]; double s = 0.0;
#pragma unroll
    for (int k2 = 0; k2 < 5; ++k2) { ex[k2] = exp(mv[k2] - m); s += ex[k2]; }
    float* po = out + BSZ * TSZ + ((size_t)b * TSZ + t) * 5;
#pragma unroll
    for (int k2 = 0; k2 < 5; ++k2) po[k2] = (float)(ex[k2] / s);
  }
  for (int k = lane; k < ESZ; k += 64)
    xt0[(size_t)k * 64 + b] = (double)embed[(size_t)nxt * ESZ + k];
}

// -------- initial embedding of SOS --------
__global__ __launch_bounds__(256) void k_emb0(const float* __restrict__ embed, const int* __restrict__ sos,
                                              double* __restrict__ xt0) {
  int idx = blockIdx.x * 256 + threadIdx.x;
  int b = idx & 63, k = idx >> 6;
  xt0[(size_t)k * 64 + b] = (double)embed[(size_t)sos[0] * ESZ + k];
}

extern "C" void kernel_launch(void* const* d_in, const int* in_sizes, int n_in,
                              void* d_out, int out_size, void* d_ws, size_t ws_size,
                              hipStream_t stream) {
  const float* hours = (const float*)d_in[0];
  const float* tp_w1 = (const float*)d_in[1];
  const float* tp_b1 = (const float*)d_in[2];
  const float* tp_w2 = (const float*)d_in[3];
  const float* tp_b2 = (const float*)d_in[4];
  const float* embed = (const float*)d_in[5];
  const float* w_ih0 = (const float*)d_in[6];
  const float* w_hh0 = (const float*)d_in[7];
  const float* b0    = (const float*)d_in[8];
  const float* w_ih1 = (const float*)d_in[9];
  const float* w_hh1 = (const float*)d_in[10];
  const float* b1    = (const float*)d_in[11];
  const float* fc_w  = (const float*)d_in[12];
  const float* fc_b  = (const float*)d_in[13];
  const int*   sos   = (const int*)d_in[14];
  float* out = (float*)d_out;

  char* w = (char*)d_ws;
  double* part = (double*)w;  w += (size_t)NSLOT * 64 * GC * 8;   // 54.5 MB lstm partials
  double* xt0  = (double*)w;  w += (size_t)ESZ * 64 * 8;
  double* h0T  = (double*)w;  w += (size_t)HSZ * 64 * 8;
  double* h1T  = (double*)w;  w += (size_t)HSZ * 64 * 8;
  double* c0   = (double*)w;  w += (size_t)BSZ * HSZ * 8;
  double* c1   = (double*)w;  w += (size_t)BSZ * HSZ * 8;
  double* tp1T = (double*)w;  w += (size_t)HSZ * 64 * 8;
  double* gum  = (double*)w;  w += (size_t)TSZ * 320 * 8;
  double* candV = (double*)w; w += (size_t)BSZ * NCAND * 8;       // 2.01 MB, b-major
  int*    candI = (int*)w;    w += (size_t)BSZ * NCAND * 4;       // 1.01 MB
  int*    fbuf  = (int*)w;    w += 64;                            // [0]=conv

  k_probe<<<dim3(1), dim3(64), 0, stream>>>(fbuf);
  k_rng<<<dim3(100), dim3(256), 0, stream>>>(gum);
  k_time1<<<dim3(256), dim3(256), 0, stream>>>(hours, tp_w1, tp_b1, tp1T);
  k_gemm_simple<<<dim3(16, 8), dim3(256), 0, stream>>>(tp1T, tp_w2, 1024, 8, part);
  k_t2r<<<dim3(16, 64), dim3(256), 0, stream>>>(part, tp_b2, h0T, c0, h1T, c1);
  k_emb0<<<dim3(64), dim3(256), 0, stream>>>(embed, sos, xt0);

  double* part18 = part + (size_t)18 * 64 * GC;
  for (int t = 0; t < TSZ; ++t) {
    // A: slices 0-1 = xt0*w_ih0, 2-9 = h0*w_hh0, 10-17 = h1*w_hh1 -> slots 0..17
    k_lstm_mfma<<<dim3(64, 18), dim3(256), 0, stream>>>(xt0, w_ih0, h0T, w_hh0, h1T, w_hh1, 2, 10, part, fbuf);
    k_cell<<<dim3(4, 64), dim3(256), 0, stream>>>(part, 0, 10, b0, c0, h0T);
    // B: slices 0-7 = h0n*w_ih1 -> slots 18..25
    k_lstm_mfma<<<dim3(64, 8), dim3(256), 0, stream>>>(h0T, w_ih1, h0T, w_ih1, h0T, w_ih1, 8, 8, part18, fbuf);
    k_cell<<<dim3(4, 64), dim3(256), 0, stream>>>(part, 10, 16, b1, c1, h1T);
    k_fcmfma<<<dim3(NFCB), dim3(256), 0, stream>>>(h1T, fc_w, fc_b, candV, candI, fbuf);
    k_fin<<<dim3(64), dim3(64), 0, stream>>>(candV, candI, gum, t, embed, out, xt0);
  }
}